// Round 4
// baseline (382.286 us; speedup 1.0000x reference)
//
#include <hip/hip_runtime.h>
#include <math.h>

#define DI __device__ __forceinline__

namespace {

constexpr int PB = 32768;   // batch

typedef _Float16 half_t;
typedef float f32x4 __attribute__((ext_vector_type(4)));
typedef _Float16 f16x8 __attribute__((ext_vector_type(8)));
typedef unsigned int u32x4 __attribute__((ext_vector_type(4)));

#define MFMA16 __builtin_amdgcn_mfma_f32_16x16x32_f16

// ---------------- precompute kernels (all tiny) ----------------

__global__ void k_weff(const float* __restrict__ Wqkv, const float* __restrict__ bqkv,
                       const float* __restrict__ Wo, const float* __restrict__ bo,
                       float* __restrict__ M, float* __restrict__ beff)
{
  const int i = blockIdx.x >> 7;
  const int c = blockIdx.x & 127;
  const int k = threadIdx.x;
  const float* wo_row = Wo + (size_t)(i*128 + c)*128;
  const float* wv = Wqkv + (size_t)(i*384 + 256)*128;
  float acc = 0.f;
#pragma unroll 4
  for (int j = 0; j < 128; ++j)
    acc = fmaf(wo_row[j], wv[j*128 + k], acc);
  M[(size_t)(i*128 + c)*128 + k] = acc;

  __shared__ float red[128];
  const float* bv = bqkv + i*384 + 256;
  red[k] = wo_row[k] * bv[k];
  __syncthreads();
  for (int s = 64; s > 0; s >>= 1) {
    if (k < s) red[k] += red[k + s];
    __syncthreads();
  }
  if (k == 0) beff[i*128 + c] = red[0] + bo[i*128 + c];
}

__global__ void k_nbig2(const float* __restrict__ Wf1, const float* __restrict__ M,
                        const float* __restrict__ beff,
                        half_t* __restrict__ Nh, half_t* __restrict__ Nl)
{
  const int i = blockIdx.x >> 8;
  const int c = blockIdx.x & 255;
  const int k = threadIdx.x;
  const float* w_row = Wf1 + (size_t)c*768 + i*128;
  const float* Mi = M + (size_t)i*128*128;
  float acc = 0.f;
#pragma unroll 4
  for (int j = 0; j < 128; ++j)
    acc = fmaf(w_row[j], Mi[j*128 + k], acc);
  float v = acc * 4096.f;
  half_t hi = (half_t)v;
  Nh[(size_t)c*800 + i*128 + k] = hi;
  Nl[(size_t)c*800 + i*128 + k] = (half_t)(v - (float)hi);

  __shared__ float red[128];
  red[k] = w_row[k] * beff[i*128 + k];
  __syncthreads();
  for (int s = 64; s > 0; s >>= 1) {
    if (k < s) red[k] += red[k + s];
    __syncthreads();
  }
  if (k == 0) {
    float cv = red[0] * 4096.f;
    half_t ch = (half_t)cv;
    Nh[(size_t)c*800 + 768 + i] = ch;
    Nl[(size_t)c*800 + 768 + i] = (half_t)(cv - (float)ch);
  }
  if (i == 0 && k < 26) {
    Nh[(size_t)c*800 + 774 + k] = (half_t)0.f;
    Nl[(size_t)c*800 + 774 + k] = (half_t)0.f;
  }
}

__global__ void k_ghat(const float* __restrict__ M, const float* __restrict__ Wg,
                       float* __restrict__ Ghat)
{
  const int j = blockIdx.x / 3;
  const int src = blockIdx.x % 3;
  const int k = threadIdx.x;
  int i0, i1;
  if (src == 0)      { i0 = 2; i1 = 4; }
  else if (src == 1) { i0 = 0; i1 = 5; }
  else               { i0 = 1; i1 = 3; }
  float acc = 0.f;
  for (int t = 0; t < 2; ++t) {
    const int i = t ? i1 : i0;
    const float* Mi = M + (size_t)i*128*128;
    const float* wg = Wg + j*768 + i*128;
#pragma unroll 4
    for (int c = 0; c < 128; ++c)
      acc = fmaf(Mi[c*128 + k], wg[c], acc);
  }
  Ghat[j*384 + src*128 + k] = acc;
}

__global__ void k_svec(const float* __restrict__ beff, const float* __restrict__ Wg,
                       const float* __restrict__ bg, float* __restrict__ svec)
{
  const int j = blockIdx.x;
  const int c = threadIdx.x;
  float p = 0.f;
#pragma unroll
  for (int i = 0; i < 6; ++i)
    p = fmaf(beff[i*128 + c], Wg[j*768 + i*128 + c], p);
  __shared__ float red[128];
  red[c] = p;
  __syncthreads();
  for (int s = 64; s > 0; s >>= 1) {
    if (c < s) red[c] += red[c + s];
    __syncthreads();
  }
  if (c == 0) svec[j] = red[0] + bg[j];
}

__global__ void k_split(const float* __restrict__ in, half_t* __restrict__ hi,
                        half_t* __restrict__ lo, float scale, int n)
{
  const int i = blockIdx.x*256 + threadIdx.x;
  if (i < n) {
    float v = in[i] * scale;
    half_t h = (half_t)v;
    hi[i] = h;
    lo[i] = (half_t)(v - (float)h);
  }
}

// ================= proj: 128x128 tile, reg-direct A and B, NO LDS, no barriers =================
template<int KD>
DI void proj_body(const float* __restrict__ X, const half_t* __restrict__ Bh_,
                  const half_t* __restrict__ Bl_, const float* __restrict__ bias,
                  const float* __restrict__ lnw, const float* __restrict__ lnb,
                  const float* __restrict__ Ghat, float* __restrict__ tva,
                  float* __restrict__ zpart, int row0, int colOff, int srcIdx)
{
  const int tid = threadIdx.x;
  const int lane = tid & 63, wid = tid >> 6;
  const int l15 = lane & 15, l4 = lane >> 4;
  constexpr int NT = KD >> 5;
  const int r0 = row0 + wid*32;

  const float* xr0 = X + (size_t)(r0 + l15)*KD + l4*8;
  const float* xr1 = X + (size_t)(r0 + 16 + l15)*KD + l4*8;
  const half_t* bhp = Bh_ + (size_t)l15*KD + l4*8;
  const half_t* blp = Bl_ + (size_t)l15*KD + l4*8;

  f32x4 ra[2][2];
  auto LOADA = [&](int t) {
    const f32x4* p0 = reinterpret_cast<const f32x4*>(xr0 + t*32);
    const f32x4* p1 = reinterpret_cast<const f32x4*>(xr1 + t*32);
    ra[0][0] = p0[0]; ra[0][1] = p0[1];
    ra[1][0] = p1[0]; ra[1][1] = p1[1];
  };
  f16x8 aH[2], aL[2];
  auto SPLIT = [&]() {
#pragma unroll
    for (int rg = 0; rg < 2; ++rg) {
      float e[8] = {ra[rg][0][0], ra[rg][0][1], ra[rg][0][2], ra[rg][0][3],
                    ra[rg][1][0], ra[rg][1][1], ra[rg][1][2], ra[rg][1][3]};
      f16x8 hv, lv;
#pragma unroll
      for (int j = 0; j < 8; ++j) {
        half_t h = (half_t)e[j];
        hv[j] = h; lv[j] = (half_t)(e[j] - (float)h);
      }
      aH[rg] = hv; aL[rg] = lv;
    }
  };

  f32x4 acc[2][8];
#pragma unroll
  for (int rg = 0; rg < 2; ++rg)
#pragma unroll
    for (int fn = 0; fn < 8; ++fn) acc[rg][fn] = f32x4{0.f, 0.f, 0.f, 0.f};

  LOADA(0);
  for (int t = 0; t < NT; ++t) {
    SPLIT();
    if (t + 1 < NT) LOADA(t + 1);
#pragma unroll
    for (int fn = 0; fn < 8; ++fn) {
      f16x8 bH = *reinterpret_cast<const f16x8*>(bhp + (size_t)fn*16*KD + t*32);
      f16x8 bL = *reinterpret_cast<const f16x8*>(blp + (size_t)fn*16*KD + t*32);
#pragma unroll
      for (int rg = 0; rg < 2; ++rg) {
        acc[rg][fn] = MFMA16(aH[rg], bH, acc[rg][fn], 0, 0, 0);
        acc[rg][fn] = MFMA16(aH[rg], bL, acc[rg][fn], 0, 0, 0);
        acc[rg][fn] = MFMA16(aL[rg], bH, acc[rg][fn], 0, 0, 0);
      }
    }
  }

  // epilogue: descale+bias, LN over 128 cols (16-lane shfl), ReLU, store tva, z-partials
  float bc[8], lw[8], lb[8], gh[6][8];
#pragma unroll
  for (int fn = 0; fn < 8; ++fn) {
    const int c = fn*16 + l15;
    bc[fn] = bias[c]; lw[fn] = lnw[c]; lb[fn] = lnb[c];
#pragma unroll
    for (int j = 0; j < 6; ++j) gh[j][fn] = Ghat[j*384 + colOff + c];
  }
#pragma unroll
  for (int rg = 0; rg < 2; ++rg) {
#pragma unroll
    for (int r = 0; r < 4; ++r) {
      float h[8];
      float s = 0.f, q = 0.f;
#pragma unroll
      for (int fn = 0; fn < 8; ++fn) {
        h[fn] = acc[rg][fn][r]*(1.f/256.f) + bc[fn];
        s += h[fn]; q = fmaf(h[fn], h[fn], q);
      }
#pragma unroll
      for (int m = 1; m <= 8; m <<= 1) { s += __shfl_xor(s, m); q += __shfl_xor(q, m); }
      const float mean = s*(1.f/128.f);
      const float var  = q*(1.f/128.f) - mean*mean;
      const float rstd = rsqrtf(var + 1e-5f);
      float o[8];
#pragma unroll
      for (int fn = 0; fn < 8; ++fn)
        o[fn] = fmaxf(fmaf((h[fn] - mean)*rstd, lw[fn], lb[fn]), 0.f);
      const int grow = r0 + rg*16 + l4*4 + r;
      float* tp = tva + (size_t)grow*384 + colOff;
#pragma unroll
      for (int fn = 0; fn < 8; ++fn) tp[fn*16 + l15] = o[fn];
      float s6[6];
#pragma unroll
      for (int j = 0; j < 6; ++j) {
        float z = 0.f;
#pragma unroll
        for (int fn = 0; fn < 8; ++fn) z = fmaf(o[fn], gh[j][fn], z);
#pragma unroll
        for (int m = 1; m <= 8; m <<= 1) z += __shfl_xor(z, m);
        s6[j] = z;
      }
#pragma unroll
      for (int j = 0; j < 6; ++j)
        if (l15 == j) zpart[(size_t)(srcIdx*PB + grow)*6 + j] = s6[j];
    }
  }
}

__global__ __launch_bounds__(256, 3)
void k_proj(const float* __restrict__ xt, const float* __restrict__ xv,
            const float* __restrict__ xa, const half_t* __restrict__ Whall,
            const half_t* __restrict__ Wlall,
            const float* __restrict__ bt, const float* __restrict__ lnwt, const float* __restrict__ lnbt,
            const float* __restrict__ bvp, const float* __restrict__ lnwv, const float* __restrict__ lnbv,
            const float* __restrict__ bap, const float* __restrict__ lnwa, const float* __restrict__ lnba,
            const float* __restrict__ Ghat, float* __restrict__ tva, float* __restrict__ zpart)
{
  const int src = blockIdx.y;
  const int row0 = blockIdx.x * 128;
  if (src == 0)
    proj_body<768>(xt, Whall, Wlall, bt, lnwt, lnbt, Ghat, tva, zpart, row0, 0, 0);
  else if (src == 1)
    proj_body<512>(xv, Whall + 98304, Wlall + 98304, bvp, lnwv, lnbv, Ghat, tva, zpart, row0, 128, 1);
  else
    proj_body<384>(xa, Whall + 163840, Wlall + 163840, bap, lnwa, lnba, Ghat, tva, zpart, row0, 256, 2);
}

// gate combine
__global__ void k_gate2(const float* __restrict__ zp, const float* __restrict__ svec,
                        float* __restrict__ g)
{
  const int r = blockIdx.x*256 + threadIdx.x;
  float z[6];
#pragma unroll
  for (int j = 0; j < 6; ++j)
    z[j] = zp[(size_t)r*6 + j] + zp[(size_t)(PB + r)*6 + j] + zp[(size_t)(2*PB + r)*6 + j] + svec[j];
  float mx = z[0];
#pragma unroll
  for (int j = 1; j < 6; ++j) mx = fmaxf(mx, z[j]);
  float e[6], s = 0.f;
#pragma unroll
  for (int j = 0; j < 6; ++j) { e[j] = expf(z[j] - mx); s += e[j]; }
  const float inv = 1.f / s;
#pragma unroll
  for (int j = 0; j < 6; ++j) g[(size_t)r*6 + j] = e[j]*inv;
}

// ================= f1: 128x128 tile, reg-direct, gated A, K=800 (cvec cols folded) =================
__global__ __launch_bounds__(256, 2)
void k_f1(const float* __restrict__ tva, const half_t* __restrict__ Bh_,
          const half_t* __restrict__ Bl_, const float* __restrict__ gbuf,
          const float* __restrict__ bias, unsigned int* __restrict__ h1p)
{
  __shared__ float gS[768];
  const int tid = threadIdx.x;
  const int row0 = blockIdx.x * 128;
  const int colOff = blockIdx.y * 128;
  const int lane = tid & 63, wid = tid >> 6;
  const int l15 = lane & 15, l4 = lane >> 4;
  constexpr int NT = 25;
  const int r0 = row0 + wid*32;

  for (int i = tid; i < 768; i += 256) gS[i] = gbuf[(size_t)row0*6 + i];
  __syncthreads();

  const float* ar0 = tva + (size_t)(r0 + l15)*384 + l4*8;
  const float* ar1 = tva + (size_t)(r0 + 16 + l15)*384 + l4*8;
  const half_t* bhp = Bh_ + (size_t)(colOff + l15)*800 + l4*8;
  const half_t* blp = Bl_ + (size_t)(colOff + l15)*800 + l4*8;

  f32x4 ra[2][2];
  auto LOADA = [&](int t) {
    if (t < 24) {
      const int koff = ((0x102021 >> ((t >> 2)*4)) & 3)*128 + ((t*32) & 127);
      const f32x4* p0 = reinterpret_cast<const f32x4*>(ar0 + koff);
      const f32x4* p1 = reinterpret_cast<const f32x4*>(ar1 + koff);
      ra[0][0] = p0[0]; ra[0][1] = p0[1];
      ra[1][0] = p1[0]; ra[1][1] = p1[1];
    }
  };
  f16x8 aH[2], aL[2];
  auto SPLIT = [&](int t) {
#pragma unroll
    for (int rg = 0; rg < 2; ++rg) {
      const int lrow = wid*32 + rg*16 + l15;
      float e[8];
      if (t < 24) {
        const float gsc = gS[lrow*6 + (t >> 2)] * 16.f;
        e[0]=ra[rg][0][0]*gsc; e[1]=ra[rg][0][1]*gsc; e[2]=ra[rg][0][2]*gsc; e[3]=ra[rg][0][3]*gsc;
        e[4]=ra[rg][1][0]*gsc; e[5]=ra[rg][1][1]*gsc; e[6]=ra[rg][1][2]*gsc; e[7]=ra[rg][1][3]*gsc;
      } else {
#pragma unroll
        for (int j = 0; j < 8; ++j)
          e[j] = (l4 == 0 && j < 6) ? gS[lrow*6 + j]*16.f : 0.f;
      }
      f16x8 hv, lv;
#pragma unroll
      for (int j = 0; j < 8; ++j) {
        half_t h = (half_t)e[j];
        hv[j] = h; lv[j] = (half_t)(e[j] - (float)h);
      }
      aH[rg] = hv; aL[rg] = lv;
    }
  };

  f32x4 acc[2][8];
#pragma unroll
  for (int rg = 0; rg < 2; ++rg)
#pragma unroll
    for (int fn = 0; fn < 8; ++fn) acc[rg][fn] = f32x4{0.f, 0.f, 0.f, 0.f};

  LOADA(0);
  for (int t = 0; t < NT; ++t) {
    SPLIT(t);
    if (t + 1 < NT) LOADA(t + 1);
#pragma unroll
    for (int fn = 0; fn < 8; ++fn) {
      f16x8 bH = *reinterpret_cast<const f16x8*>(bhp + (size_t)fn*16*800 + t*32);
      f16x8 bL = *reinterpret_cast<const f16x8*>(blp + (size_t)fn*16*800 + t*32);
#pragma unroll
      for (int rg = 0; rg < 2; ++rg) {
        acc[rg][fn] = MFMA16(aH[rg], bH, acc[rg][fn], 0, 0, 0);
        acc[rg][fn] = MFMA16(aH[rg], bL, acc[rg][fn], 0, 0, 0);
        acc[rg][fn] = MFMA16(aL[rg], bH, acc[rg][fn], 0, 0, 0);
      }
    }
  }

  float bc[8];
#pragma unroll
  for (int fn = 0; fn < 8; ++fn) bc[fn] = bias[colOff + fn*16 + l15];
#pragma unroll
  for (int rg = 0; rg < 2; ++rg)
#pragma unroll
    for (int fn = 0; fn < 8; ++fn)
#pragma unroll
      for (int r = 0; r < 4; ++r) {
        float v = acc[rg][fn][r]*(1.f/65536.f) + bc[fn];
        v = fmaxf(v, 0.f) * 256.f;                       // pre-scale h1 for fp16 split
        half_t hi = (half_t)v;
        float lo = v - (float)hi;
        unsigned u = (unsigned)__builtin_bit_cast(unsigned short, hi)
                   | ((unsigned)__builtin_bit_cast(unsigned short, (half_t)lo) << 16);
        const int grow = r0 + rg*16 + l4*4 + r;
        h1p[(size_t)grow*256 + colOff + fn*16 + l15] = u;
      }
}

// ================= f2: 128x128 tile, reg-direct, K=256, fused head partials =================
__global__ __launch_bounds__(256, 2)
void k_f2(const unsigned int* __restrict__ h1p, const half_t* __restrict__ Bh_,
          const half_t* __restrict__ Bl_, const float* __restrict__ bias,
          const float* __restrict__ Wout, float* __restrict__ part)
{
  const int tid = threadIdx.x;
  const int row0 = blockIdx.x * 128;
  const int colOff = blockIdx.y * 128;
  const int lane = tid & 63, wid = tid >> 6;
  const int l15 = lane & 15, l4 = lane >> 4;
  constexpr int NT = 8;
  const int r0 = row0 + wid*32;

  const unsigned int* hr0 = h1p + (size_t)(r0 + l15)*256 + l4*8;
  const unsigned int* hr1 = h1p + (size_t)(r0 + 16 + l15)*256 + l4*8;
  const half_t* bhp = Bh_ + (size_t)(colOff + l15)*256 + l4*8;
  const half_t* blp = Bl_ + (size_t)(colOff + l15)*256 + l4*8;

  u32x4 ra[2][2];
  auto LOADA = [&](int t) {
    const u32x4* p0 = reinterpret_cast<const u32x4*>(hr0 + t*32);
    const u32x4* p1 = reinterpret_cast<const u32x4*>(hr1 + t*32);
    ra[0][0] = p0[0]; ra[0][1] = p0[1];
    ra[1][0] = p1[0]; ra[1][1] = p1[1];
  };
  f16x8 aH[2], aL[2];
  auto SPLIT = [&]() {
#pragma unroll
    for (int rg = 0; rg < 2; ++rg) {
      u32x4 v0 = ra[rg][0], v1 = ra[rg][1];
      u32x4 hv, lv;
      hv[0] = __builtin_amdgcn_perm(v0[1], v0[0], 0x05040100u);
      hv[1] = __builtin_amdgcn_perm(v0[3], v0[2], 0x05040100u);
      hv[2] = __builtin_amdgcn_perm(v1[1], v1[0], 0x05040100u);
      hv[3] = __builtin_amdgcn_perm(v1[3], v1[2], 0x05040100u);
      lv[0] = __builtin_amdgcn_perm(v0[1], v0[0], 0x07060302u);
      lv[1] = __builtin_amdgcn_perm(v0[3], v0[2], 0x07060302u);
      lv[2] = __builtin_amdgcn_perm(v1[1], v1[0], 0x07060302u);
      lv[3] = __builtin_amdgcn_perm(v1[3], v1[2], 0x07060302u);
      aH[rg] = __builtin_bit_cast(f16x8, hv);
      aL[rg] = __builtin_bit_cast(f16x8, lv);
    }
  };

  f32x4 acc[2][8];
#pragma unroll
  for (int rg = 0; rg < 2; ++rg)
#pragma unroll
    for (int fn = 0; fn < 8; ++fn) acc[rg][fn] = f32x4{0.f, 0.f, 0.f, 0.f};

  LOADA(0);
  for (int t = 0; t < NT; ++t) {
    SPLIT();
    if (t + 1 < NT) LOADA(t + 1);
#pragma unroll
    for (int fn = 0; fn < 8; ++fn) {
      f16x8 bH = *reinterpret_cast<const f16x8*>(bhp + (size_t)fn*16*256 + t*32);
      f16x8 bL = *reinterpret_cast<const f16x8*>(blp + (size_t)fn*16*256 + t*32);
#pragma unroll
      for (int rg = 0; rg < 2; ++rg) {
        acc[rg][fn] = MFMA16(aH[rg], bH, acc[rg][fn], 0, 0, 0);
        acc[rg][fn] = MFMA16(aH[rg], bL, acc[rg][fn], 0, 0, 0);
        acc[rg][fn] = MFMA16(aL[rg], bH, acc[rg][fn], 0, 0, 0);
      }
    }
  }

  // epilogue: relu(h2), partial dot with Wout over this block's 128 cols
  float bc[8], w0[8], w1[8];
#pragma unroll
  for (int fn = 0; fn < 8; ++fn) {
    const int c = colOff + fn*16 + l15;
    bc[fn] = bias[c]; w0[fn] = Wout[c]; w1[fn] = Wout[256 + c];
  }
#pragma unroll
  for (int rg = 0; rg < 2; ++rg)
#pragma unroll
    for (int r = 0; r < 4; ++r) {
      float s0 = 0.f, s1 = 0.f;
#pragma unroll
      for (int fn = 0; fn < 8; ++fn) {
        float hv = fmaxf(acc[rg][fn][r]*(1.f/65536.f) + bc[fn], 0.f);
        s0 = fmaf(hv, w0[fn], s0);
        s1 = fmaf(hv, w1[fn], s1);
      }
#pragma unroll
      for (int m = 1; m <= 8; m <<= 1) { s0 += __shfl_xor(s0, m); s1 += __shfl_xor(s1, m); }
      if (l15 == rg*4 + r) {
        const int grow = r0 + rg*16 + l4*4 + r;
        float* pp = part + ((size_t)blockIdx.y*PB + grow)*2;
        pp[0] = s0; pp[1] = s1;
      }
    }
}

__global__ void k_comb(const float* __restrict__ part, const float* __restrict__ bout,
                       float* __restrict__ out)
{
  const int id = blockIdx.x*256 + threadIdx.x;
  const int j = id & 1;
  float s = bout[j];
#pragma unroll
  for (int s2 = 0; s2 < 2; ++s2) s += part[(size_t)s2*PB*2 + id];
  out[id] = s;
}

} // namespace

extern "C" void kernel_launch(void* const* d_in, const int* in_sizes, int n_in,
                              void* d_out, int out_size, void* d_ws, size_t ws_size,
                              hipStream_t stream)
{
  const float* xt   = (const float*)d_in[0];
  const float* xv   = (const float*)d_in[1];
  const float* xa   = (const float*)d_in[2];
  const float* Wt   = (const float*)d_in[3];
  const float* bt   = (const float*)d_in[4];
  const float* lnwt = (const float*)d_in[5];
  const float* lnbt = (const float*)d_in[6];
  const float* Wv   = (const float*)d_in[7];
  const float* bv   = (const float*)d_in[8];
  const float* lnwv = (const float*)d_in[9];
  const float* lnbv = (const float*)d_in[10];
  const float* Wa   = (const float*)d_in[11];
  const float* ba   = (const float*)d_in[12];
  const float* lnwa = (const float*)d_in[13];
  const float* lnba = (const float*)d_in[14];
  const float* Wqkv = (const float*)d_in[15];
  const float* bqkv = (const float*)d_in[16];
  const float* Wo   = (const float*)d_in[17];
  const float* bo   = (const float*)d_in[18];
  const float* Wg   = (const float*)d_in[19];
  const float* bg   = (const float*)d_in[20];
  const float* Wf1  = (const float*)d_in[21];
  const float* bf1  = (const float*)d_in[22];
  const float* Wf2  = (const float*)d_in[23];
  const float* bf2  = (const float*)d_in[24];
  const float* Woutp= (const float*)d_in[25];
  const float* boutp= (const float*)d_in[26];
  float* out = (float*)d_out;

  float* ws   = (float*)d_ws;
  float* tva  = ws;                              // PB*384
  float* g    = tva  + (size_t)PB*384;           // PB*6
  float* h1pf = g    + (size_t)PB*6;             // PB*256 u32
  float* M    = h1pf + (size_t)PB*256;           // 98304
  float* beff = M    + 98304;                    // 768
  half_t* Nh   = (half_t*)(beff + 768);          // 204800 h
  half_t* Nl   = Nh + 204800;
  half_t* Whall= Nl + 204800;                    // 212992 h  [t|v|a]
  half_t* Wlall= Whall + 212992;
  half_t* Wf2h = Wlall + 212992;                 // 65536 h
  half_t* Wf2l = Wf2h + 65536;
  float* Ghat  = (float*)(Wf2l + 65536);         // 2304
  float* svec  = Ghat + 2304;                    // 8
  unsigned int* h1p = (unsigned int*)h1pf;
  float* zpart = h1pf;                           // 3*PB*6, dead before f1 writes h1p
  float* part  = tva;                            // 2*PB*2, tva dead before f2

  // weight composition + splits
  k_weff<<<768, 128, 0, stream>>>(Wqkv, bqkv, Wo, bo, M, beff);
  k_nbig2<<<1536, 128, 0, stream>>>(Wf1, M, beff, Nh, Nl);
  k_ghat<<<18, 128, 0, stream>>>(M, Wg, Ghat);
  k_svec<<<6, 128, 0, stream>>>(beff, Wg, bg, svec);
  k_split<<<(128*768 + 255)/256, 256, 0, stream>>>(Wt, Whall, Wlall, 256.f, 128*768);
  k_split<<<(128*512 + 255)/256, 256, 0, stream>>>(Wv, Whall + 98304, Wlall + 98304, 256.f, 128*512);
  k_split<<<(128*384 + 255)/256, 256, 0, stream>>>(Wa, Whall + 163840, Wlall + 163840, 256.f, 128*384);
  k_split<<<(256*256 + 255)/256, 256, 0, stream>>>(Wf2, Wf2h, Wf2l, 256.f, 256*256);

  // merged projections (fused LN+ReLU+gate-partials)
  k_proj<<<dim3(256, 3), 256, 0, stream>>>(xt, xv, xa, Whall, Wlall,
                                           bt, lnwt, lnbt, bv, lnwv, lnbv, ba, lnwa, lnba,
                                           Ghat, tva, zpart);

  // gate
  k_gate2<<<PB/256, 256, 0, stream>>>(zpart, svec, g);

  // f1 (gated fused branch+f1, cvec folded, K=800), f2 (fused head partials), combine
  k_f1<<<dim3(256, 2), 256, 0, stream>>>(tva, Nh, Nl, g, bf1, h1p);
  k_f2<<<dim3(256, 2), 256, 0, stream>>>(h1p, Wf2h, Wf2l, bf2, Woutp, part);
  k_comb<<<256, 256, 0, stream>>>(part, boutp, out);
}

// Round 5
// 213.647 us; speedup vs baseline: 1.7893x; 1.7893x over previous
//
#include <hip/hip_runtime.h>
#include <math.h>

#define DI __device__ __forceinline__

namespace {

constexpr int PB = 32768;   // batch

typedef _Float16 half_t;
typedef float f32x4 __attribute__((ext_vector_type(4)));
typedef _Float16 f16x8 __attribute__((ext_vector_type(8)));
typedef unsigned int u32x4 __attribute__((ext_vector_type(4)));

#define MFMA16 __builtin_amdgcn_mfma_f32_16x16x32_f16

DI void gl16(const void* g, void* l) {
  __builtin_amdgcn_global_load_lds((const __attribute__((address_space(1))) void*)g,
                                   (__attribute__((address_space(3))) void*)l, 16, 0, 0);
}
DI f16x8 asH(f32x4 v) { return __builtin_bit_cast(f16x8, v); }

// fragment-major index for a P-col, KD-row-of-k weight plane pair:
// idx(t,pl,c,k) = ((t*2+pl)*(P/16) + (c>>4))*512 + ((k>>3)&3)*128 + (c&15)*8 + (k&7)
DI size_t fragIdx(int c, int k, int P) {
  return (size_t)(((k >> 5) * 2) * (P >> 4) + (c >> 4)) * 512
       + ((k >> 3) & 3) * 128 + (c & 15) * 8 + (k & 7);
}

// ---------------- precompute kernels (all tiny) ----------------

__global__ void k_weff(const float* __restrict__ Wqkv, const float* __restrict__ bqkv,
                       const float* __restrict__ Wo, const float* __restrict__ bo,
                       float* __restrict__ M, float* __restrict__ beff)
{
  const int i = blockIdx.x >> 7;
  const int c = blockIdx.x & 127;
  const int k = threadIdx.x;
  const float* wo_row = Wo + (size_t)(i*128 + c)*128;
  const float* wv = Wqkv + (size_t)(i*384 + 256)*128;
  float acc = 0.f;
#pragma unroll 4
  for (int j = 0; j < 128; ++j)
    acc = fmaf(wo_row[j], wv[j*128 + k], acc);
  M[(size_t)(i*128 + c)*128 + k] = acc;

  __shared__ float red[128];
  const float* bv = bqkv + i*384 + 256;
  red[k] = wo_row[k] * bv[k];
  __syncthreads();
  for (int s = 64; s > 0; s >>= 1) {
    if (k < s) red[k] += red[k + s];
    __syncthreads();
  }
  if (k == 0) beff[i*128 + c] = red[0] + bo[i*128 + c];
}

// N fragments (P=256, K=800): value 4096*(Wf1·M); kg=768+i column = 4096*cvec_i; pad zero
__global__ void k_nbig2(const float* __restrict__ Wf1, const float* __restrict__ M,
                        const float* __restrict__ beff, half_t* __restrict__ Nf)
{
  const int i = blockIdx.x >> 8;
  const int c = blockIdx.x & 255;
  const int k = threadIdx.x;
  const float* w_row = Wf1 + (size_t)c*768 + i*128;
  const float* Mi = M + (size_t)i*128*128;
  float acc = 0.f;
#pragma unroll 4
  for (int j = 0; j < 128; ++j)
    acc = fmaf(w_row[j], Mi[j*128 + k], acc);
  float v = acc * 4096.f;
  half_t hi = (half_t)v;
  const int kg = i*128 + k;
  size_t o = fragIdx(c, kg, 256);
  Nf[o] = hi;
  Nf[o + 16*512] = (half_t)(v - (float)hi);

  __shared__ float red[128];
  red[k] = w_row[k] * beff[i*128 + k];
  __syncthreads();
  for (int s = 64; s > 0; s >>= 1) {
    if (k < s) red[k] += red[k + s];
    __syncthreads();
  }
  if (k == 0) {
    float cv = red[0] * 4096.f;
    half_t ch = (half_t)cv;
    size_t oc = fragIdx(c, 768 + i, 256);
    Nf[oc] = ch;
    Nf[oc + 16*512] = (half_t)(cv - (float)ch);
  }
  if (i == 0 && k < 26) {
    size_t oz = fragIdx(c, 774 + k, 256);
    Nf[oz] = (half_t)0.f;
    Nf[oz + 16*512] = (half_t)0.f;
  }
}

__global__ void k_ghat(const float* __restrict__ M, const float* __restrict__ Wg,
                       float* __restrict__ Ghat)
{
  const int j = blockIdx.x / 3;
  const int src = blockIdx.x % 3;
  const int k = threadIdx.x;
  int i0, i1;
  if (src == 0)      { i0 = 2; i1 = 4; }
  else if (src == 1) { i0 = 0; i1 = 5; }
  else               { i0 = 1; i1 = 3; }
  float acc = 0.f;
  for (int t = 0; t < 2; ++t) {
    const int i = t ? i1 : i0;
    const float* Mi = M + (size_t)i*128*128;
    const float* wg = Wg + j*768 + i*128;
#pragma unroll 4
    for (int c = 0; c < 128; ++c)
      acc = fmaf(Mi[c*128 + k], wg[c], acc);
  }
  Ghat[j*384 + src*128 + k] = acc;
}

__global__ void k_svec(const float* __restrict__ beff, const float* __restrict__ Wg,
                       const float* __restrict__ bg, float* __restrict__ svec)
{
  const int j = blockIdx.x;
  const int c = threadIdx.x;
  float p = 0.f;
#pragma unroll
  for (int i = 0; i < 6; ++i)
    p = fmaf(beff[i*128 + c], Wg[j*768 + i*128 + c], p);
  __shared__ float red[128];
  red[c] = p;
  __syncthreads();
  for (int s = 64; s > 0; s >>= 1) {
    if (c < s) red[c] += red[c + s];
    __syncthreads();
  }
  if (c == 0) svec[j] = red[0] + bg[j];
}

// split fp32 weight -> scaled fp16 hi/lo planes in FRAGMENT-MAJOR layout
__global__ void k_splitf(const float* __restrict__ in, half_t* __restrict__ outb,
                         float scale, int P, int KD)
{
  const int idx = blockIdx.x*256 + threadIdx.x;
  if (idx >= P*KD) return;
  const int c = idx / KD, k = idx - c*KD;
  float v = in[idx] * scale;
  half_t h = (half_t)v;
  size_t o = fragIdx(c, k, P);
  outb[o] = h;
  outb[o + (size_t)(P >> 4)*512] = (half_t)(v - (float)h);
}

// ================= proj: 64x128 tile, 2 waves, gl16-staged frag-major B, reg A =================
template<int KD>
DI void proj_body(const float* __restrict__ X, const half_t* __restrict__ BF,
                  const float* __restrict__ bias,
                  const float* __restrict__ lnw, const float* __restrict__ lnb,
                  const float* __restrict__ Ghat, float* __restrict__ tva,
                  float* __restrict__ zpart, int row0, int colOff, int srcIdx,
                  f32x4* Bs)
{
  const int tid = threadIdx.x;
  const int lane = tid & 63, wid = tid >> 6;
  const int l15 = lane & 15, l4 = lane >> 4;
  constexpr int NT = KD >> 5;
  const int r0 = row0 + wid*32;

  const float* xr0 = X + (size_t)(r0 + l15)*KD + l4*8;
  const float* xr1 = X + (size_t)(r0 + 16 + l15)*KD + l4*8;

  auto STAGE = [&](int t, int buf) {
    const half_t* s0 = BF + (size_t)t*8192;          // pl0 slice (8KB)
    const half_t* s1 = s0 + 4096;                    // pl1
#pragma unroll
    for (int q = 0; q < 4; ++q) {
      const int ch = wid*4 + q;
      gl16(s0 + ch*512 + lane*8, &Bs[buf*1024 + ch*64]);
      gl16(s1 + ch*512 + lane*8, &Bs[buf*1024 + 512 + ch*64]);
    }
  };

  f32x4 ra[2][2];
  auto LOADA = [&](int t) {
    const f32x4* p0 = reinterpret_cast<const f32x4*>(xr0 + t*32);
    const f32x4* p1 = reinterpret_cast<const f32x4*>(xr1 + t*32);
    ra[0][0] = p0[0]; ra[0][1] = p0[1];
    ra[1][0] = p1[0]; ra[1][1] = p1[1];
  };
  f16x8 aH[2], aL[2];
  auto SPLIT = [&]() {
#pragma unroll
    for (int rg = 0; rg < 2; ++rg) {
      float e[8] = {ra[rg][0][0], ra[rg][0][1], ra[rg][0][2], ra[rg][0][3],
                    ra[rg][1][0], ra[rg][1][1], ra[rg][1][2], ra[rg][1][3]};
      f16x8 hv, lv;
#pragma unroll
      for (int j = 0; j < 8; ++j) {
        half_t h = (half_t)e[j];
        hv[j] = h; lv[j] = (half_t)(e[j] - (float)h);
      }
      aH[rg] = hv; aL[rg] = lv;
    }
  };

  f32x4 acc[2][8];
#pragma unroll
  for (int rg = 0; rg < 2; ++rg)
#pragma unroll
    for (int fn = 0; fn < 8; ++fn) acc[rg][fn] = f32x4{0.f, 0.f, 0.f, 0.f};

  STAGE(0, 0); LOADA(0);
  __syncthreads();
  for (int t = 0; t < NT; ++t) {
    const int cur = t & 1;
    if (t + 1 < NT) STAGE(t + 1, cur ^ 1);
    SPLIT();
    if (t + 1 < NT) LOADA(t + 1);
#pragma unroll
    for (int fn = 0; fn < 8; ++fn) {
      f16x8 bH = asH(Bs[cur*1024 + fn*64 + lane]);
      f16x8 bL = asH(Bs[cur*1024 + 512 + fn*64 + lane]);
      acc[0][fn] = MFMA16(aH[0], bH, acc[0][fn], 0, 0, 0);
      acc[0][fn] = MFMA16(aH[0], bL, acc[0][fn], 0, 0, 0);
      acc[0][fn] = MFMA16(aL[0], bH, acc[0][fn], 0, 0, 0);
      acc[1][fn] = MFMA16(aH[1], bH, acc[1][fn], 0, 0, 0);
      acc[1][fn] = MFMA16(aH[1], bL, acc[1][fn], 0, 0, 0);
      acc[1][fn] = MFMA16(aL[1], bH, acc[1][fn], 0, 0, 0);
    }
    __syncthreads();
  }

  // epilogue: descale+bias, LN over 128 cols (16-lane shfl), ReLU, store tva, z-partials
  float bc[8], lw[8], lb[8], gh[6][8];
#pragma unroll
  for (int fn = 0; fn < 8; ++fn) {
    const int c = fn*16 + l15;
    bc[fn] = bias[c]; lw[fn] = lnw[c]; lb[fn] = lnb[c];
#pragma unroll
    for (int j = 0; j < 6; ++j) gh[j][fn] = Ghat[j*384 + colOff + c];
  }
#pragma unroll
  for (int rg = 0; rg < 2; ++rg) {
#pragma unroll
    for (int r = 0; r < 4; ++r) {
      float h[8];
      float s = 0.f, q = 0.f;
#pragma unroll
      for (int fn = 0; fn < 8; ++fn) {
        h[fn] = acc[rg][fn][r]*(1.f/256.f) + bc[fn];
        s += h[fn]; q = fmaf(h[fn], h[fn], q);
      }
#pragma unroll
      for (int m = 1; m <= 8; m <<= 1) { s += __shfl_xor(s, m); q += __shfl_xor(q, m); }
      const float mean = s*(1.f/128.f);
      const float var  = q*(1.f/128.f) - mean*mean;
      const float rstd = rsqrtf(var + 1e-5f);
      float o[8];
#pragma unroll
      for (int fn = 0; fn < 8; ++fn)
        o[fn] = fmaxf(fmaf((h[fn] - mean)*rstd, lw[fn], lb[fn]), 0.f);
      const int grow = r0 + rg*16 + l4*4 + r;
      float* tp = tva + (size_t)grow*384 + colOff;
#pragma unroll
      for (int fn = 0; fn < 8; ++fn) tp[fn*16 + l15] = o[fn];
      float s6[6];
#pragma unroll
      for (int j = 0; j < 6; ++j) {
        float z = 0.f;
#pragma unroll
        for (int fn = 0; fn < 8; ++fn) z = fmaf(o[fn], gh[j][fn], z);
#pragma unroll
        for (int m = 1; m <= 8; m <<= 1) z += __shfl_xor(z, m);
        s6[j] = z;
      }
#pragma unroll
      for (int j = 0; j < 6; ++j)
        if (l15 == j) zpart[(size_t)(srcIdx*PB + grow)*6 + j] = s6[j];
    }
  }
}

__global__ __launch_bounds__(128, 2)
void k_proj(const float* __restrict__ xt, const float* __restrict__ xv,
            const float* __restrict__ xa, const half_t* __restrict__ Wft,
            const half_t* __restrict__ Wfv, const half_t* __restrict__ Wfa,
            const float* __restrict__ bt, const float* __restrict__ lnwt, const float* __restrict__ lnbt,
            const float* __restrict__ bvp, const float* __restrict__ lnwv, const float* __restrict__ lnbv,
            const float* __restrict__ bap, const float* __restrict__ lnwa, const float* __restrict__ lnba,
            const float* __restrict__ Ghat, float* __restrict__ tva, float* __restrict__ zpart)
{
  __shared__ f32x4 Bs[2048];
  const int src = blockIdx.y;
  const int row0 = blockIdx.x * 64;
  if (src == 0)
    proj_body<768>(xt, Wft, bt, lnwt, lnbt, Ghat, tva, zpart, row0, 0, 0, Bs);
  else if (src == 1)
    proj_body<512>(xv, Wfv, bvp, lnwv, lnbv, Ghat, tva, zpart, row0, 128, 1, Bs);
  else
    proj_body<384>(xa, Wfa, bap, lnwa, lnba, Ghat, tva, zpart, row0, 256, 2, Bs);
}

// gate combine
__global__ void k_gate2(const float* __restrict__ zp, const float* __restrict__ svec,
                        float* __restrict__ g)
{
  const int r = blockIdx.x*256 + threadIdx.x;
  float z[6];
#pragma unroll
  for (int j = 0; j < 6; ++j)
    z[j] = zp[(size_t)r*6 + j] + zp[(size_t)(PB + r)*6 + j] + zp[(size_t)(2*PB + r)*6 + j] + svec[j];
  float mx = z[0];
#pragma unroll
  for (int j = 1; j < 6; ++j) mx = fmaxf(mx, z[j]);
  float e[6], s = 0.f;
#pragma unroll
  for (int j = 0; j < 6; ++j) { e[j] = expf(z[j] - mx); s += e[j]; }
  const float inv = 1.f / s;
#pragma unroll
  for (int j = 0; j < 6; ++j) g[(size_t)r*6 + j] = e[j]*inv;
}

// ================= f1: 64x128 tile, 2 waves, staged frag-major N, gated reg A, K=800 =================
__global__ __launch_bounds__(128, 2)
void k_f1(const float* __restrict__ tva, const half_t* __restrict__ Nf,
          const float* __restrict__ gbuf, const float* __restrict__ bias,
          unsigned int* __restrict__ h1p)
{
  __shared__ f32x4 Bs[2048];
  __shared__ float gS[384];
  const int tid = threadIdx.x;
  const int row0 = blockIdx.x * 64;
  const int colOff = blockIdx.y * 128;
  const int fn0 = colOff >> 4;
  const int lane = tid & 63, wid = tid >> 6;
  const int l15 = lane & 15, l4 = lane >> 4;
  constexpr int NT = 25;
  const int r0 = row0 + wid*32;

  for (int i = tid; i < 384; i += 128) gS[i] = gbuf[(size_t)row0*6 + i];

  const float* ar0 = tva + (size_t)(r0 + l15)*384 + l4*8;
  const float* ar1 = tva + (size_t)(r0 + 16 + l15)*384 + l4*8;

  auto STAGE = [&](int t, int buf) {
    const half_t* s0 = Nf + (size_t)t*16384 + fn0*512;
    const half_t* s1 = s0 + 8192;
#pragma unroll
    for (int q = 0; q < 4; ++q) {
      const int ch = wid*4 + q;
      gl16(s0 + ch*512 + lane*8, &Bs[buf*1024 + ch*64]);
      gl16(s1 + ch*512 + lane*8, &Bs[buf*1024 + 512 + ch*64]);
    }
  };

  f32x4 ra[2][2];
  auto LOADA = [&](int t) {
    if (t < 24) {
      const int koff = ((0x102021 >> ((t >> 2)*4)) & 3)*128 + (t & 3)*32;
      const f32x4* p0 = reinterpret_cast<const f32x4*>(ar0 + koff);
      const f32x4* p1 = reinterpret_cast<const f32x4*>(ar1 + koff);
      ra[0][0] = p0[0]; ra[0][1] = p0[1];
      ra[1][0] = p1[0]; ra[1][1] = p1[1];
    }
  };
  f16x8 aH[2], aL[2];
  auto SPLIT = [&](int t) {
#pragma unroll
    for (int rg = 0; rg < 2; ++rg) {
      const int lrow = wid*32 + rg*16 + l15;
      float e[8];
      if (t < 24) {
        const float gsc = gS[lrow*6 + (t >> 2)] * 16.f;
        e[0]=ra[rg][0][0]*gsc; e[1]=ra[rg][0][1]*gsc; e[2]=ra[rg][0][2]*gsc; e[3]=ra[rg][0][3]*gsc;
        e[4]=ra[rg][1][0]*gsc; e[5]=ra[rg][1][1]*gsc; e[6]=ra[rg][1][2]*gsc; e[7]=ra[rg][1][3]*gsc;
      } else {
#pragma unroll
        for (int j = 0; j < 8; ++j)
          e[j] = (l4 == 0 && j < 6) ? gS[lrow*6 + j]*16.f : 0.f;
      }
      f16x8 hv, lv;
#pragma unroll
      for (int j = 0; j < 8; ++j) {
        half_t h = (half_t)e[j];
        hv[j] = h; lv[j] = (half_t)(e[j] - (float)h);
      }
      aH[rg] = hv; aL[rg] = lv;
    }
  };

  f32x4 acc[2][8];
#pragma unroll
  for (int rg = 0; rg < 2; ++rg)
#pragma unroll
    for (int fn = 0; fn < 8; ++fn) acc[rg][fn] = f32x4{0.f, 0.f, 0.f, 0.f};

  STAGE(0, 0); LOADA(0);
  __syncthreads();
  for (int t = 0; t < NT; ++t) {
    const int cur = t & 1;
    if (t + 1 < NT) STAGE(t + 1, cur ^ 1);
    SPLIT(t);
    if (t + 1 < NT) LOADA(t + 1);
#pragma unroll
    for (int fn = 0; fn < 8; ++fn) {
      f16x8 bH = asH(Bs[cur*1024 + fn*64 + lane]);
      f16x8 bL = asH(Bs[cur*1024 + 512 + fn*64 + lane]);
      acc[0][fn] = MFMA16(aH[0], bH, acc[0][fn], 0, 0, 0);
      acc[0][fn] = MFMA16(aH[0], bL, acc[0][fn], 0, 0, 0);
      acc[0][fn] = MFMA16(aL[0], bH, acc[0][fn], 0, 0, 0);
      acc[1][fn] = MFMA16(aH[1], bH, acc[1][fn], 0, 0, 0);
      acc[1][fn] = MFMA16(aH[1], bL, acc[1][fn], 0, 0, 0);
      acc[1][fn] = MFMA16(aL[1], bH, acc[1][fn], 0, 0, 0);
    }
    __syncthreads();
  }

  float bc[8];
#pragma unroll
  for (int fn = 0; fn < 8; ++fn) bc[fn] = bias[colOff + fn*16 + l15];
#pragma unroll
  for (int rg = 0; rg < 2; ++rg)
#pragma unroll
    for (int fn = 0; fn < 8; ++fn)
#pragma unroll
      for (int r = 0; r < 4; ++r) {
        float v = acc[rg][fn][r]*(1.f/65536.f) + bc[fn];
        v = fmaxf(v, 0.f) * 256.f;                       // pre-scale h1 for fp16 split
        half_t hi = (half_t)v;
        float lo = v - (float)hi;
        unsigned u = (unsigned)__builtin_bit_cast(unsigned short, hi)
                   | ((unsigned)__builtin_bit_cast(unsigned short, (half_t)lo) << 16);
        const int grow = r0 + rg*16 + l4*4 + r;
        h1p[(size_t)grow*256 + colOff + fn*16 + l15] = u;
      }
}

// ================= f2: 64x128 tile, 2 waves, staged frag-major Wf2, K=256, fused head =================
__global__ __launch_bounds__(128, 2)
void k_f2(const unsigned int* __restrict__ h1p, const half_t* __restrict__ WF,
          const float* __restrict__ bias, const float* __restrict__ Wout,
          float* __restrict__ part)
{
  __shared__ f32x4 Bs[2048];
  const int tid = threadIdx.x;
  const int row0 = blockIdx.x * 64;
  const int colOff = blockIdx.y * 128;
  const int fn0 = colOff >> 4;
  const int lane = tid & 63, wid = tid >> 6;
  const int l15 = lane & 15, l4 = lane >> 4;
  constexpr int NT = 8;
  const int r0 = row0 + wid*32;

  const unsigned int* hr0 = h1p + (size_t)(r0 + l15)*256 + l4*8;
  const unsigned int* hr1 = h1p + (size_t)(r0 + 16 + l15)*256 + l4*8;

  auto STAGE = [&](int t, int buf) {
    const half_t* s0 = WF + (size_t)t*16384 + fn0*512;
    const half_t* s1 = s0 + 8192;
#pragma unroll
    for (int q = 0; q < 4; ++q) {
      const int ch = wid*4 + q;
      gl16(s0 + ch*512 + lane*8, &Bs[buf*1024 + ch*64]);
      gl16(s1 + ch*512 + lane*8, &Bs[buf*1024 + 512 + ch*64]);
    }
  };

  u32x4 ra[2][2];
  auto LOADA = [&](int t) {
    const u32x4* p0 = reinterpret_cast<const u32x4*>(hr0 + t*32);
    const u32x4* p1 = reinterpret_cast<const u32x4*>(hr1 + t*32);
    ra[0][0] = p0[0]; ra[0][1] = p0[1];
    ra[1][0] = p1[0]; ra[1][1] = p1[1];
  };
  f16x8 aH[2], aL[2];
  auto SPLIT = [&]() {
#pragma unroll
    for (int rg = 0; rg < 2; ++rg) {
      u32x4 v0 = ra[rg][0], v1 = ra[rg][1];
      u32x4 hv, lv;
      hv[0] = __builtin_amdgcn_perm(v0[1], v0[0], 0x05040100u);
      hv[1] = __builtin_amdgcn_perm(v0[3], v0[2], 0x05040100u);
      hv[2] = __builtin_amdgcn_perm(v1[1], v1[0], 0x05040100u);
      hv[3] = __builtin_amdgcn_perm(v1[3], v1[2], 0x05040100u);
      lv[0] = __builtin_amdgcn_perm(v0[1], v0[0], 0x07060302u);
      lv[1] = __builtin_amdgcn_perm(v0[3], v0[2], 0x07060302u);
      lv[2] = __builtin_amdgcn_perm(v1[1], v1[0], 0x07060302u);
      lv[3] = __builtin_amdgcn_perm(v1[3], v1[2], 0x07060302u);
      aH[rg] = __builtin_bit_cast(f16x8, hv);
      aL[rg] = __builtin_bit_cast(f16x8, lv);
    }
  };

  f32x4 acc[2][8];
#pragma unroll
  for (int rg = 0; rg < 2; ++rg)
#pragma unroll
    for (int fn = 0; fn < 8; ++fn) acc[rg][fn] = f32x4{0.f, 0.f, 0.f, 0.f};

  STAGE(0, 0); LOADA(0);
  __syncthreads();
  for (int t = 0; t < NT; ++t) {
    const int cur = t & 1;
    if (t + 1 < NT) STAGE(t + 1, cur ^ 1);
    SPLIT();
    if (t + 1 < NT) LOADA(t + 1);
#pragma unroll
    for (int fn = 0; fn < 8; ++fn) {
      f16x8 bH = asH(Bs[cur*1024 + fn*64 + lane]);
      f16x8 bL = asH(Bs[cur*1024 + 512 + fn*64 + lane]);
      acc[0][fn] = MFMA16(aH[0], bH, acc[0][fn], 0, 0, 0);
      acc[0][fn] = MFMA16(aH[0], bL, acc[0][fn], 0, 0, 0);
      acc[0][fn] = MFMA16(aL[0], bH, acc[0][fn], 0, 0, 0);
      acc[1][fn] = MFMA16(aH[1], bH, acc[1][fn], 0, 0, 0);
      acc[1][fn] = MFMA16(aH[1], bL, acc[1][fn], 0, 0, 0);
      acc[1][fn] = MFMA16(aL[1], bH, acc[1][fn], 0, 0, 0);
    }
    __syncthreads();
  }

  // epilogue: relu(h2), partial dot with Wout over this block's 128 cols
  float bc[8], w0[8], w1[8];
#pragma unroll
  for (int fn = 0; fn < 8; ++fn) {
    const int c = colOff + fn*16 + l15;
    bc[fn] = bias[c]; w0[fn] = Wout[c]; w1[fn] = Wout[256 + c];
  }
#pragma unroll
  for (int rg = 0; rg < 2; ++rg)
#pragma unroll
    for (int r = 0; r < 4; ++r) {
      float s0 = 0.f, s1 = 0.f;
#pragma unroll
      for (int fn = 0; fn < 8; ++fn) {
        float hv = fmaxf(acc[rg][fn][r]*(1.f/65536.f) + bc[fn], 0.f);
        s0 = fmaf(hv, w0[fn], s0);
        s1 = fmaf(hv, w1[fn], s1);
      }
#pragma unroll
      for (int m = 1; m <= 8; m <<= 1) { s0 += __shfl_xor(s0, m); s1 += __shfl_xor(s1, m); }
      if (l15 == rg*4 + r) {
        const int grow = r0 + rg*16 + l4*4 + r;
        float* pp = part + ((size_t)blockIdx.y*PB + grow)*2;
        pp[0] = s0; pp[1] = s1;
      }
    }
}

__global__ void k_comb(const float* __restrict__ part, const float* __restrict__ bout,
                       float* __restrict__ out)
{
  const int id = blockIdx.x*256 + threadIdx.x;
  const int j = id & 1;
  float s = bout[j];
#pragma unroll
  for (int s2 = 0; s2 < 2; ++s2) s += part[(size_t)s2*PB*2 + id];
  out[id] = s;
}

} // namespace

extern "C" void kernel_launch(void* const* d_in, const int* in_sizes, int n_in,
                              void* d_out, int out_size, void* d_ws, size_t ws_size,
                              hipStream_t stream)
{
  const float* xt   = (const float*)d_in[0];
  const float* xv   = (const float*)d_in[1];
  const float* xa   = (const float*)d_in[2];
  const float* Wt   = (const float*)d_in[3];
  const float* bt   = (const float*)d_in[4];
  const float* lnwt = (const float*)d_in[5];
  const float* lnbt = (const float*)d_in[6];
  const float* Wv   = (const float*)d_in[7];
  const float* bv   = (const float*)d_in[8];
  const float* lnwv = (const float*)d_in[9];
  const float* lnbv = (const float*)d_in[10];
  const float* Wa   = (const float*)d_in[11];
  const float* ba   = (const float*)d_in[12];
  const float* lnwa = (const float*)d_in[13];
  const float* lnba = (const float*)d_in[14];
  const float* Wqkv = (const float*)d_in[15];
  const float* bqkv = (const float*)d_in[16];
  const float* Wo   = (const float*)d_in[17];
  const float* bo   = (const float*)d_in[18];
  const float* Wg   = (const float*)d_in[19];
  const float* bg   = (const float*)d_in[20];
  const float* Wf1  = (const float*)d_in[21];
  const float* bf1  = (const float*)d_in[22];
  const float* Wf2  = (const float*)d_in[23];
  const float* bf2  = (const float*)d_in[24];
  const float* Woutp= (const float*)d_in[25];
  const float* boutp= (const float*)d_in[26];
  float* out = (float*)d_out;

  float* ws   = (float*)d_ws;
  float* tva  = ws;                              // PB*384 f32
  float* g    = tva  + (size_t)PB*384;           // PB*6
  float* h1pf = g    + (size_t)PB*6;             // PB*256 u32
  float* M    = h1pf + (size_t)PB*256;           // 98304
  float* beff = M    + 98304;                    // 768
  half_t* Wft = (half_t*)(beff + 768);           // 24*8192 = 196608 h
  half_t* Wfv = Wft + 196608;                    // 16*8192 = 131072 h
  half_t* Wfa = Wfv + 131072;                    // 12*8192 =  98304 h
  half_t* Nf  = Wfa + 98304;                     // 25*16384 = 409600 h
  half_t* WF2 = Nf + 409600;                     //  8*16384 = 131072 h
  float* Ghat = (float*)(WF2 + 131072);          // 2304
  float* svec = Ghat + 2304;                     // 8
  unsigned int* h1p = (unsigned int*)h1pf;
  float* zpart = h1pf;                           // 3*PB*6, dead before f1 writes h1p
  float* part  = tva;                            // 2*PB*2, tva dead before f2

  // weight composition + fragment-major splits
  k_weff<<<768, 128, 0, stream>>>(Wqkv, bqkv, Wo, bo, M, beff);
  k_nbig2<<<1536, 128, 0, stream>>>(Wf1, M, beff, Nf);
  k_ghat<<<18, 128, 0, stream>>>(M, Wg, Ghat);
  k_svec<<<6, 128, 0, stream>>>(beff, Wg, bg, svec);
  k_splitf<<<(128*768 + 255)/256, 256, 0, stream>>>(Wt, Wft, 256.f, 128, 768);
  k_splitf<<<(128*512 + 255)/256, 256, 0, stream>>>(Wv, Wfv, 256.f, 128, 512);
  k_splitf<<<(128*384 + 255)/256, 256, 0, stream>>>(Wa, Wfa, 256.f, 128, 384);
  k_splitf<<<(256*256 + 255)/256, 256, 0, stream>>>(Wf2, WF2, 256.f, 256, 256);

  // merged projections (fused LN+ReLU+gate-partials)
  k_proj<<<dim3(512, 3), 128, 0, stream>>>(xt, xv, xa, Wft, Wfv, Wfa,
                                           bt, lnwt, lnbt, bv, lnwv, lnbv, ba, lnwa, lnba,
                                           Ghat, tva, zpart);

  // gate
  k_gate2<<<PB/256, 256, 0, stream>>>(zpart, svec, g);

  // f1 (gated fused branch+f1, cvec folded, K=800), f2 (fused head partials), combine
  k_f1<<<dim3(512, 2), 128, 0, stream>>>(tva, Nf, g, bf1, h1p);
  k_f2<<<dim3(512, 2), 128, 0, stream>>>(h1p, WF2, bf2, Woutp, part);
  k_comb<<<256, 256, 0, stream>>>(part, boutp, out);
}

// Round 6
// 208.627 us; speedup vs baseline: 1.8324x; 1.0241x over previous
//
#include <hip/hip_runtime.h>
#include <math.h>

#define DI __device__ __forceinline__

namespace {

constexpr int PB = 32768;   // batch

typedef _Float16 half_t;
typedef float f32x4 __attribute__((ext_vector_type(4)));
typedef _Float16 f16x8 __attribute__((ext_vector_type(8)));
typedef unsigned int u32x4 __attribute__((ext_vector_type(4)));

#define MFMA16 __builtin_amdgcn_mfma_f32_16x16x32_f16

DI void gl16(const void* g, void* l) {
  __builtin_amdgcn_global_load_lds((const __attribute__((address_space(1))) void*)g,
                                   (__attribute__((address_space(3))) void*)l, 16, 0, 0);
}
DI f16x8 asH(f32x4 v) { return __builtin_bit_cast(f16x8, v); }

// fragment-major index for a P-col, KD-row-of-k weight plane pair:
// idx(t,pl,c,k) = ((t*2+pl)*(P/16) + (c>>4))*512 + ((k>>3)&3)*128 + (c&15)*8 + (k&7)
DI size_t fragIdx(int c, int k, int P) {
  return (size_t)(((k >> 5) * 2) * (P >> 4) + (c >> 4)) * 512
       + ((k >> 3) & 3) * 128 + (c & 15) * 8 + (k & 7);
}

// ---------------- precompute kernels (all tiny) ----------------

__global__ void k_weff(const float* __restrict__ Wqkv, const float* __restrict__ bqkv,
                       const float* __restrict__ Wo, const float* __restrict__ bo,
                       float* __restrict__ M, float* __restrict__ beff)
{
  const int i = blockIdx.x >> 7;
  const int c = blockIdx.x & 127;
  const int k = threadIdx.x;
  const float* wo_row = Wo + (size_t)(i*128 + c)*128;
  const float* wv = Wqkv + (size_t)(i*384 + 256)*128;
  float acc = 0.f;
#pragma unroll 4
  for (int j = 0; j < 128; ++j)
    acc = fmaf(wo_row[j], wv[j*128 + k], acc);
  M[(size_t)(i*128 + c)*128 + k] = acc;

  __shared__ float red[128];
  const float* bv = bqkv + i*384 + 256;
  red[k] = wo_row[k] * bv[k];
  __syncthreads();
  for (int s = 64; s > 0; s >>= 1) {
    if (k < s) red[k] += red[k + s];
    __syncthreads();
  }
  if (k == 0) beff[i*128 + c] = red[0] + bo[i*128 + c];
}

// N fragments (P=256, K=800): value 4096*(Wf1·M); kg=768+i column = 4096*cvec_i; pad zero
__global__ void k_nbig2(const float* __restrict__ Wf1, const float* __restrict__ M,
                        const float* __restrict__ beff, half_t* __restrict__ Nf)
{
  const int i = blockIdx.x >> 8;
  const int c = blockIdx.x & 255;
  const int k = threadIdx.x;
  const float* w_row = Wf1 + (size_t)c*768 + i*128;
  const float* Mi = M + (size_t)i*128*128;
  float acc = 0.f;
#pragma unroll 4
  for (int j = 0; j < 128; ++j)
    acc = fmaf(w_row[j], Mi[j*128 + k], acc);
  float v = acc * 4096.f;
  half_t hi = (half_t)v;
  const int kg = i*128 + k;
  size_t o = fragIdx(c, kg, 256);
  Nf[o] = hi;
  Nf[o + 16*512] = (half_t)(v - (float)hi);

  __shared__ float red[128];
  red[k] = w_row[k] * beff[i*128 + k];
  __syncthreads();
  for (int s = 64; s > 0; s >>= 1) {
    if (k < s) red[k] += red[k + s];
    __syncthreads();
  }
  if (k == 0) {
    float cv = red[0] * 4096.f;
    half_t ch = (half_t)cv;
    size_t oc = fragIdx(c, 768 + i, 256);
    Nf[oc] = ch;
    Nf[oc + 16*512] = (half_t)(cv - (float)ch);
  }
  if (i == 0 && k < 26) {
    size_t oz = fragIdx(c, 774 + k, 256);
    Nf[oz] = (half_t)0.f;
    Nf[oz + 16*512] = (half_t)0.f;
  }
}

__global__ void k_ghat(const float* __restrict__ M, const float* __restrict__ Wg,
                       float* __restrict__ Ghat)
{
  const int j = blockIdx.x / 3;
  const int src = blockIdx.x % 3;
  const int k = threadIdx.x;
  int i0, i1;
  if (src == 0)      { i0 = 2; i1 = 4; }
  else if (src == 1) { i0 = 0; i1 = 5; }
  else               { i0 = 1; i1 = 3; }
  float acc = 0.f;
  for (int t = 0; t < 2; ++t) {
    const int i = t ? i1 : i0;
    const float* Mi = M + (size_t)i*128*128;
    const float* wg = Wg + j*768 + i*128;
#pragma unroll 4
    for (int c = 0; c < 128; ++c)
      acc = fmaf(Mi[c*128 + k], wg[c], acc);
  }
  Ghat[j*384 + src*128 + k] = acc;
}

__global__ void k_svec(const float* __restrict__ beff, const float* __restrict__ Wg,
                       const float* __restrict__ bg, float* __restrict__ svec)
{
  const int j = blockIdx.x;
  const int c = threadIdx.x;
  float p = 0.f;
#pragma unroll
  for (int i = 0; i < 6; ++i)
    p = fmaf(beff[i*128 + c], Wg[j*768 + i*128 + c], p);
  __shared__ float red[128];
  red[c] = p;
  __syncthreads();
  for (int s = 64; s > 0; s >>= 1) {
    if (c < s) red[c] += red[c + s];
    __syncthreads();
  }
  if (c == 0) svec[j] = red[0] + bg[j];
}

// split fp32 weight -> scaled fp16 hi/lo planes in FRAGMENT-MAJOR layout
__global__ void k_splitf(const float* __restrict__ in, half_t* __restrict__ outb,
                         float scale, int P, int KD)
{
  const int idx = blockIdx.x*256 + threadIdx.x;
  if (idx >= P*KD) return;
  const int c = idx / KD, k = idx - c*KD;
  float v = in[idx] * scale;
  half_t h = (half_t)v;
  size_t o = fragIdx(c, k, P);
  outb[o] = h;
  outb[o + (size_t)(P >> 4)*512] = (half_t)(v - (float)h);
}

// ================= proj: 128x128 tile, 4 waves, gl16-staged frag-major B, reg A =================
template<int KD>
DI void proj_body(const float* __restrict__ X, const half_t* __restrict__ BF,
                  const float* __restrict__ bias,
                  const float* __restrict__ lnw, const float* __restrict__ lnb,
                  const float* __restrict__ Ghat, float* __restrict__ tva,
                  float* __restrict__ zpart, int row0, int colOff, int srcIdx,
                  f32x4* Bs)
{
  const int tid = threadIdx.x;
  const int lane = tid & 63, wid = tid >> 6;
  const int l15 = lane & 15, l4 = lane >> 4;
  constexpr int NT = KD >> 5;
  const int r0 = row0 + wid*32;

  const float* xr0 = X + (size_t)(r0 + l15)*KD + l4*8;
  const float* xr1 = X + (size_t)(r0 + 16 + l15)*KD + l4*8;

  auto STAGE = [&](int t, int buf) {
    const half_t* s = BF + (size_t)t*8192;   // 16 chunks of 512 halfs (pl0 fn0-7, pl1 fn0-7)
#pragma unroll
    for (int q = 0; q < 4; ++q) {
      const int ch = wid*4 + q;
      gl16(s + ch*512 + lane*8, &Bs[buf*1024 + ch*64]);
    }
  };

  f32x4 ra[2][2];
  auto LOADA = [&](int t) {
    const f32x4* p0 = reinterpret_cast<const f32x4*>(xr0 + t*32);
    const f32x4* p1 = reinterpret_cast<const f32x4*>(xr1 + t*32);
    ra[0][0] = p0[0]; ra[0][1] = p0[1];
    ra[1][0] = p1[0]; ra[1][1] = p1[1];
  };
  f16x8 aH[2], aL[2];
  auto SPLIT = [&]() {
#pragma unroll
    for (int rg = 0; rg < 2; ++rg) {
      float e[8] = {ra[rg][0][0], ra[rg][0][1], ra[rg][0][2], ra[rg][0][3],
                    ra[rg][1][0], ra[rg][1][1], ra[rg][1][2], ra[rg][1][3]};
      f16x8 hv, lv;
#pragma unroll
      for (int j = 0; j < 8; ++j) {
        half_t h = (half_t)e[j];
        hv[j] = h; lv[j] = (half_t)(e[j] - (float)h);
      }
      aH[rg] = hv; aL[rg] = lv;
    }
  };

  f32x4 acc[2][8];
#pragma unroll
  for (int rg = 0; rg < 2; ++rg)
#pragma unroll
    for (int fn = 0; fn < 8; ++fn) acc[rg][fn] = f32x4{0.f, 0.f, 0.f, 0.f};

  STAGE(0, 0); LOADA(0);
  __syncthreads();
  for (int t = 0; t < NT; ++t) {
    const int cur = t & 1;
    if (t + 1 < NT) STAGE(t + 1, cur ^ 1);
    SPLIT();
    if (t + 1 < NT) LOADA(t + 1);
#pragma unroll
    for (int fn = 0; fn < 8; ++fn) {
      f16x8 bH = asH(Bs[cur*1024 + fn*64 + lane]);
      f16x8 bL = asH(Bs[cur*1024 + 512 + fn*64 + lane]);
      acc[0][fn] = MFMA16(aH[0], bH, acc[0][fn], 0, 0, 0);
      acc[0][fn] = MFMA16(aH[0], bL, acc[0][fn], 0, 0, 0);
      acc[0][fn] = MFMA16(aL[0], bH, acc[0][fn], 0, 0, 0);
      acc[1][fn] = MFMA16(aH[1], bH, acc[1][fn], 0, 0, 0);
      acc[1][fn] = MFMA16(aH[1], bL, acc[1][fn], 0, 0, 0);
      acc[1][fn] = MFMA16(aL[1], bH, acc[1][fn], 0, 0, 0);
    }
    __syncthreads();
  }

  // epilogue: descale+bias, LN over 128 cols (16-lane shfl), ReLU, store tva, z-partials
  float bc[8], lw[8], lb[8], gh[6][8];
#pragma unroll
  for (int fn = 0; fn < 8; ++fn) {
    const int c = fn*16 + l15;
    bc[fn] = bias[c]; lw[fn] = lnw[c]; lb[fn] = lnb[c];
#pragma unroll
    for (int j = 0; j < 6; ++j) gh[j][fn] = Ghat[j*384 + colOff + c];
  }
#pragma unroll
  for (int rg = 0; rg < 2; ++rg) {
#pragma unroll
    for (int r = 0; r < 4; ++r) {
      float h[8];
      float s = 0.f, q = 0.f;
#pragma unroll
      for (int fn = 0; fn < 8; ++fn) {
        h[fn] = acc[rg][fn][r]*(1.f/256.f) + bc[fn];
        s += h[fn]; q = fmaf(h[fn], h[fn], q);
      }
#pragma unroll
      for (int m = 1; m <= 8; m <<= 1) { s += __shfl_xor(s, m); q += __shfl_xor(q, m); }
      const float mean = s*(1.f/128.f);
      const float var  = q*(1.f/128.f) - mean*mean;
      const float rstd = rsqrtf(var + 1e-5f);
      float o[8];
#pragma unroll
      for (int fn = 0; fn < 8; ++fn)
        o[fn] = fmaxf(fmaf((h[fn] - mean)*rstd, lw[fn], lb[fn]), 0.f);
      const int grow = r0 + rg*16 + l4*4 + r;
      float* tp = tva + (size_t)grow*384 + colOff;
#pragma unroll
      for (int fn = 0; fn < 8; ++fn) tp[fn*16 + l15] = o[fn];
      float s6[6];
#pragma unroll
      for (int j = 0; j < 6; ++j) {
        float z = 0.f;
#pragma unroll
        for (int fn = 0; fn < 8; ++fn) z = fmaf(o[fn], gh[j][fn], z);
#pragma unroll
        for (int m = 1; m <= 8; m <<= 1) z += __shfl_xor(z, m);
        s6[j] = z;
      }
#pragma unroll
      for (int j = 0; j < 6; ++j)
        if (l15 == j) zpart[(size_t)(srcIdx*PB + grow)*6 + j] = s6[j];
    }
  }
}

__global__ __launch_bounds__(256, 3)
void k_proj(const float* __restrict__ xt, const float* __restrict__ xv,
            const float* __restrict__ xa, const half_t* __restrict__ Wft,
            const half_t* __restrict__ Wfv, const half_t* __restrict__ Wfa,
            const float* __restrict__ bt, const float* __restrict__ lnwt, const float* __restrict__ lnbt,
            const float* __restrict__ bvp, const float* __restrict__ lnwv, const float* __restrict__ lnbv,
            const float* __restrict__ bap, const float* __restrict__ lnwa, const float* __restrict__ lnba,
            const float* __restrict__ Ghat, float* __restrict__ tva, float* __restrict__ zpart)
{
  __shared__ f32x4 Bs[2048];
  const int src = blockIdx.y;
  const int row0 = blockIdx.x * 128;
  if (src == 0)
    proj_body<768>(xt, Wft, bt, lnwt, lnbt, Ghat, tva, zpart, row0, 0, 0, Bs);
  else if (src == 1)
    proj_body<512>(xv, Wfv, bvp, lnwv, lnbv, Ghat, tva, zpart, row0, 128, 1, Bs);
  else
    proj_body<384>(xa, Wfa, bap, lnwa, lnba, Ghat, tva, zpart, row0, 256, 2, Bs);
}

// gate combine
__global__ void k_gate2(const float* __restrict__ zp, const float* __restrict__ svec,
                        float* __restrict__ g)
{
  const int r = blockIdx.x*256 + threadIdx.x;
  float z[6];
#pragma unroll
  for (int j = 0; j < 6; ++j)
    z[j] = zp[(size_t)r*6 + j] + zp[(size_t)(PB + r)*6 + j] + zp[(size_t)(2*PB + r)*6 + j] + svec[j];
  float mx = z[0];
#pragma unroll
  for (int j = 1; j < 6; ++j) mx = fmaxf(mx, z[j]);
  float e[6], s = 0.f;
#pragma unroll
  for (int j = 0; j < 6; ++j) { e[j] = expf(z[j] - mx); s += e[j]; }
  const float inv = 1.f / s;
#pragma unroll
  for (int j = 0; j < 6; ++j) g[(size_t)r*6 + j] = e[j]*inv;
}

// ================= f1: 128x128 tile, 4 waves, staged frag-major N, gated reg A, K=800 =================
__global__ __launch_bounds__(256, 4)
void k_f1(const float* __restrict__ tva, const half_t* __restrict__ Nf,
          const float* __restrict__ gbuf, const float* __restrict__ bias,
          unsigned int* __restrict__ h1p)
{
  __shared__ f32x4 Bs[2048];
  __shared__ float gS[768];
  const int tid = threadIdx.x;
  const int row0 = blockIdx.x * 128;
  const int colOff = blockIdx.y * 128;
  const int fn0 = colOff >> 4;
  const int lane = tid & 63, wid = tid >> 6;
  const int l15 = lane & 15, l4 = lane >> 4;
  constexpr int NT = 25;
  const int r0 = row0 + wid*32;

  for (int i = tid; i < 768; i += 256) gS[i] = gbuf[(size_t)row0*6 + i];

  const float* ar0 = tva + (size_t)(r0 + l15)*384 + l4*8;
  const float* ar1 = tva + (size_t)(r0 + 16 + l15)*384 + l4*8;

  auto STAGE = [&](int t, int buf) {
    const half_t* s = Nf + (size_t)t*16384;
#pragma unroll
    for (int q = 0; q < 4; ++q) {
      const int ch = wid*4 + q;           // 0..15: pl = ch>>3, fn = ch&7
      gl16(s + (ch >> 3)*8192 + (fn0 + (ch & 7))*512 + lane*8, &Bs[buf*1024 + ch*64]);
    }
  };

  f32x4 ra[2][2];
  auto LOADA = [&](int t) {
    if (t < 24) {
      const int koff = ((0x102021 >> ((t >> 2)*4)) & 3)*128 + (t & 3)*32;
      const f32x4* p0 = reinterpret_cast<const f32x4*>(ar0 + koff);
      const f32x4* p1 = reinterpret_cast<const f32x4*>(ar1 + koff);
      ra[0][0] = p0[0]; ra[0][1] = p0[1];
      ra[1][0] = p1[0]; ra[1][1] = p1[1];
    }
  };
  f16x8 aH[2], aL[2];
  auto SPLIT = [&](int t) {
#pragma unroll
    for (int rg = 0; rg < 2; ++rg) {
      const int lrow = wid*32 + rg*16 + l15;
      float e[8];
      if (t < 24) {
        const float gsc = gS[lrow*6 + (t >> 2)] * 16.f;
        e[0]=ra[rg][0][0]*gsc; e[1]=ra[rg][0][1]*gsc; e[2]=ra[rg][0][2]*gsc; e[3]=ra[rg][0][3]*gsc;
        e[4]=ra[rg][1][0]*gsc; e[5]=ra[rg][1][1]*gsc; e[6]=ra[rg][1][2]*gsc; e[7]=ra[rg][1][3]*gsc;
      } else {
#pragma unroll
        for (int j = 0; j < 8; ++j)
          e[j] = (l4 == 0 && j < 6) ? gS[lrow*6 + j]*16.f : 0.f;
      }
      f16x8 hv, lv;
#pragma unroll
      for (int j = 0; j < 8; ++j) {
        half_t h = (half_t)e[j];
        hv[j] = h; lv[j] = (half_t)(e[j] - (float)h);
      }
      aH[rg] = hv; aL[rg] = lv;
    }
  };

  f32x4 acc[2][8];
#pragma unroll
  for (int rg = 0; rg < 2; ++rg)
#pragma unroll
    for (int fn = 0; fn < 8; ++fn) acc[rg][fn] = f32x4{0.f, 0.f, 0.f, 0.f};

  STAGE(0, 0); LOADA(0);
  __syncthreads();
  for (int t = 0; t < NT; ++t) {
    const int cur = t & 1;
    if (t + 1 < NT) STAGE(t + 1, cur ^ 1);
    SPLIT(t);
    if (t + 1 < NT) LOADA(t + 1);
#pragma unroll
    for (int fn = 0; fn < 8; ++fn) {
      f16x8 bH = asH(Bs[cur*1024 + fn*64 + lane]);
      f16x8 bL = asH(Bs[cur*1024 + 512 + fn*64 + lane]);
      acc[0][fn] = MFMA16(aH[0], bH, acc[0][fn], 0, 0, 0);
      acc[0][fn] = MFMA16(aH[0], bL, acc[0][fn], 0, 0, 0);
      acc[0][fn] = MFMA16(aL[0], bH, acc[0][fn], 0, 0, 0);
      acc[1][fn] = MFMA16(aH[1], bH, acc[1][fn], 0, 0, 0);
      acc[1][fn] = MFMA16(aH[1], bL, acc[1][fn], 0, 0, 0);
      acc[1][fn] = MFMA16(aL[1], bH, acc[1][fn], 0, 0, 0);
    }
    __syncthreads();
  }

  float bc[8];
#pragma unroll
  for (int fn = 0; fn < 8; ++fn) bc[fn] = bias[colOff + fn*16 + l15];
#pragma unroll
  for (int rg = 0; rg < 2; ++rg)
#pragma unroll
    for (int fn = 0; fn < 8; ++fn)
#pragma unroll
      for (int r = 0; r < 4; ++r) {
        float v = acc[rg][fn][r]*(1.f/65536.f) + bc[fn];
        v = fmaxf(v, 0.f) * 256.f;                       // pre-scale h1 for fp16 split
        half_t hi = (half_t)v;
        float lo = v - (float)hi;
        unsigned u = (unsigned)__builtin_bit_cast(unsigned short, hi)
                   | ((unsigned)__builtin_bit_cast(unsigned short, (half_t)lo) << 16);
        const int grow = r0 + rg*16 + l4*4 + r;
        h1p[(size_t)grow*256 + colOff + fn*16 + l15] = u;
      }
}

// ================= f2: 128x128 tile, 4 waves, staged frag-major Wf2, K=256, fused head =================
__global__ __launch_bounds__(256, 4)
void k_f2(const unsigned int* __restrict__ h1p, const half_t* __restrict__ WF,
          const float* __restrict__ bias, const float* __restrict__ Wout,
          float* __restrict__ part)
{
  __shared__ f32x4 Bs[2048];
  const int tid = threadIdx.x;
  const int row0 = blockIdx.x * 128;
  const int colOff = blockIdx.y * 128;
  const int fn0 = colOff >> 4;
  const int lane = tid & 63, wid = tid >> 6;
  const int l15 = lane & 15, l4 = lane >> 4;
  constexpr int NT = 8;
  const int r0 = row0 + wid*32;

  const unsigned int* hr0 = h1p + (size_t)(r0 + l15)*256 + l4*8;
  const unsigned int* hr1 = h1p + (size_t)(r0 + 16 + l15)*256 + l4*8;

  auto STAGE = [&](int t, int buf) {
    const half_t* s = WF + (size_t)t*16384;
#pragma unroll
    for (int q = 0; q < 4; ++q) {
      const int ch = wid*4 + q;
      gl16(s + (ch >> 3)*8192 + (fn0 + (ch & 7))*512 + lane*8, &Bs[buf*1024 + ch*64]);
    }
  };

  u32x4 ra[2][2];
  auto LOADA = [&](int t) {
    const u32x4* p0 = reinterpret_cast<const u32x4*>(hr0 + t*32);
    const u32x4* p1 = reinterpret_cast<const u32x4*>(hr1 + t*32);
    ra[0][0] = p0[0]; ra[0][1] = p0[1];
    ra[1][0] = p1[0]; ra[1][1] = p1[1];
  };
  f16x8 aH[2], aL[2];
  auto SPLIT = [&]() {
#pragma unroll
    for (int rg = 0; rg < 2; ++rg) {
      u32x4 v0 = ra[rg][0], v1 = ra[rg][1];
      u32x4 hv, lv;
      hv[0] = __builtin_amdgcn_perm(v0[1], v0[0], 0x05040100u);
      hv[1] = __builtin_amdgcn_perm(v0[3], v0[2], 0x05040100u);
      hv[2] = __builtin_amdgcn_perm(v1[1], v1[0], 0x05040100u);
      hv[3] = __builtin_amdgcn_perm(v1[3], v1[2], 0x05040100u);
      lv[0] = __builtin_amdgcn_perm(v0[1], v0[0], 0x07060302u);
      lv[1] = __builtin_amdgcn_perm(v0[3], v0[2], 0x07060302u);
      lv[2] = __builtin_amdgcn_perm(v1[1], v1[0], 0x07060302u);
      lv[3] = __builtin_amdgcn_perm(v1[3], v1[2], 0x07060302u);
      aH[rg] = __builtin_bit_cast(f16x8, hv);
      aL[rg] = __builtin_bit_cast(f16x8, lv);
    }
  };

  f32x4 acc[2][8];
#pragma unroll
  for (int rg = 0; rg < 2; ++rg)
#pragma unroll
    for (int fn = 0; fn < 8; ++fn) acc[rg][fn] = f32x4{0.f, 0.f, 0.f, 0.f};

  STAGE(0, 0); LOADA(0);
  __syncthreads();
  for (int t = 0; t < NT; ++t) {
    const int cur = t & 1;
    if (t + 1 < NT) STAGE(t + 1, cur ^ 1);
    SPLIT();
    if (t + 1 < NT) LOADA(t + 1);
#pragma unroll
    for (int fn = 0; fn < 8; ++fn) {
      f16x8 bH = asH(Bs[cur*1024 + fn*64 + lane]);
      f16x8 bL = asH(Bs[cur*1024 + 512 + fn*64 + lane]);
      acc[0][fn] = MFMA16(aH[0], bH, acc[0][fn], 0, 0, 0);
      acc[0][fn] = MFMA16(aH[0], bL, acc[0][fn], 0, 0, 0);
      acc[0][fn] = MFMA16(aL[0], bH, acc[0][fn], 0, 0, 0);
      acc[1][fn] = MFMA16(aH[1], bH, acc[1][fn], 0, 0, 0);
      acc[1][fn] = MFMA16(aH[1], bL, acc[1][fn], 0, 0, 0);
      acc[1][fn] = MFMA16(aL[1], bH, acc[1][fn], 0, 0, 0);
    }
    __syncthreads();
  }

  // epilogue: relu(h2), partial dot with Wout over this block's 128 cols
  float bc[8], w0[8], w1[8];
#pragma unroll
  for (int fn = 0; fn < 8; ++fn) {
    const int c = colOff + fn*16 + l15;
    bc[fn] = bias[c]; w0[fn] = Wout[c]; w1[fn] = Wout[256 + c];
  }
#pragma unroll
  for (int rg = 0; rg < 2; ++rg)
#pragma unroll
    for (int r = 0; r < 4; ++r) {
      float s0 = 0.f, s1 = 0.f;
#pragma unroll
      for (int fn = 0; fn < 8; ++fn) {
        float hv = fmaxf(acc[rg][fn][r]*(1.f/65536.f) + bc[fn], 0.f);
        s0 = fmaf(hv, w0[fn], s0);
        s1 = fmaf(hv, w1[fn], s1);
      }
#pragma unroll
      for (int m = 1; m <= 8; m <<= 1) { s0 += __shfl_xor(s0, m); s1 += __shfl_xor(s1, m); }
      if (l15 == rg*4 + r) {
        const int grow = r0 + rg*16 + l4*4 + r;
        float* pp = part + ((size_t)blockIdx.y*PB + grow)*2;
        pp[0] = s0; pp[1] = s1;
      }
    }
}

__global__ void k_comb(const float* __restrict__ part, const float* __restrict__ bout,
                       float* __restrict__ out)
{
  const int id = blockIdx.x*256 + threadIdx.x;
  const int j = id & 1;
  float s = bout[j];
#pragma unroll
  for (int s2 = 0; s2 < 2; ++s2) s += part[(size_t)s2*PB*2 + id];
  out[id] = s;
}

} // namespace

extern "C" void kernel_launch(void* const* d_in, const int* in_sizes, int n_in,
                              void* d_out, int out_size, void* d_ws, size_t ws_size,
                              hipStream_t stream)
{
  const float* xt   = (const float*)d_in[0];
  const float* xv   = (const float*)d_in[1];
  const float* xa   = (const float*)d_in[2];
  const float* Wt   = (const float*)d_in[3];
  const float* bt   = (const float*)d_in[4];
  const float* lnwt = (const float*)d_in[5];
  const float* lnbt = (const float*)d_in[6];
  const float* Wv   = (const float*)d_in[7];
  const float* bv   = (const float*)d_in[8];
  const float* lnwv = (const float*)d_in[9];
  const float* lnbv = (const float*)d_in[10];
  const float* Wa   = (const float*)d_in[11];
  const float* ba   = (const float*)d_in[12];
  const float* lnwa = (const float*)d_in[13];
  const float* lnba = (const float*)d_in[14];
  const float* Wqkv = (const float*)d_in[15];
  const float* bqkv = (const float*)d_in[16];
  const float* Wo   = (const float*)d_in[17];
  const float* bo   = (const float*)d_in[18];
  const float* Wg   = (const float*)d_in[19];
  const float* bg   = (const float*)d_in[20];
  const float* Wf1  = (const float*)d_in[21];
  const float* bf1  = (const float*)d_in[22];
  const float* Wf2  = (const float*)d_in[23];
  const float* bf2  = (const float*)d_in[24];
  const float* Woutp= (const float*)d_in[25];
  const float* boutp= (const float*)d_in[26];
  float* out = (float*)d_out;

  float* ws   = (float*)d_ws;
  float* tva  = ws;                              // PB*384 f32
  float* g    = tva  + (size_t)PB*384;           // PB*6
  float* h1pf = g    + (size_t)PB*6;             // PB*256 u32
  float* M    = h1pf + (size_t)PB*256;           // 98304
  float* beff = M    + 98304;                    // 768
  half_t* Wft = (half_t*)(beff + 768);           // 24*8192 = 196608 h
  half_t* Wfv = Wft + 196608;                    // 16*8192 = 131072 h
  half_t* Wfa = Wfv + 131072;                    // 12*8192 =  98304 h
  half_t* Nf  = Wfa + 98304;                     // 25*16384 = 409600 h
  half_t* WF2 = Nf + 409600;                     //  8*16384 = 131072 h
  float* Ghat = (float*)(WF2 + 131072);          // 2304
  float* svec = Ghat + 2304;                     // 8
  unsigned int* h1p = (unsigned int*)h1pf;
  float* zpart = h1pf;                           // 3*PB*6, dead before f1 writes h1p
  float* part  = tva;                            // 2*PB*2, tva dead before f2

  // weight composition + fragment-major splits
  k_weff<<<768, 128, 0, stream>>>(Wqkv, bqkv, Wo, bo, M, beff);
  k_nbig2<<<1536, 128, 0, stream>>>(Wf1, M, beff, Nf);
  k_ghat<<<18, 128, 0, stream>>>(M, Wg, Ghat);
  k_svec<<<6, 128, 0, stream>>>(beff, Wg, bg, svec);
  k_splitf<<<(128*768 + 255)/256, 256, 0, stream>>>(Wt, Wft, 256.f, 128, 768);
  k_splitf<<<(128*512 + 255)/256, 256, 0, stream>>>(Wv, Wfv, 256.f, 128, 512);
  k_splitf<<<(128*384 + 255)/256, 256, 0, stream>>>(Wa, Wfa, 256.f, 128, 384);
  k_splitf<<<(256*256 + 255)/256, 256, 0, stream>>>(Wf2, WF2, 256.f, 256, 256);

  // merged projections (fused LN+ReLU+gate-partials)
  k_proj<<<dim3(256, 3), 256, 0, stream>>>(xt, xv, xa, Wft, Wfv, Wfa,
                                           bt, lnwt, lnbt, bv, lnwv, lnbv, ba, lnwa, lnba,
                                           Ghat, tva, zpart);

  // gate
  k_gate2<<<PB/256, 256, 0, stream>>>(zpart, svec, g);

  // f1 (gated fused branch+f1, cvec folded, K=800), f2 (fused head partials), combine
  k_f1<<<dim3(256, 2), 256, 0, stream>>>(tva, Nf, g, bf1, h1p);
  k_f2<<<dim3(256, 2), 256, 0, stream>>>(h1p, WF2, bf2, Woutp, part);
  k_comb<<<256, 256, 0, stream>>>(part, boutp, out);
}